// Round 7
// baseline (248.367 us; speedup 1.0000x reference)
//
#include <hip/hip_runtime.h>

// Problem constants: B=4, R=16384, S=96
#define NRAYS 65536
#define NS    96
#define NI    95

// Output layout (FP32, outputs concatenated flat in return order):
//   composite_rgb   : [0,        196608)
//   composite_depth : [196608,   262144)
//   weights         : [262144,   6488064)
//   composite_point : [6488064,  6684672)
//   tau             : [6684672,  6750208)
#define OFF_RGB   0
#define OFF_DEPTH 196608
#define OFF_W     262144
#define OFF_PT    6488064
#define OFF_TAU   6684672

// ---------------------------------------------------------------------------
// Global depth min/max. depths are jnp.sort()ed along the sample axis by
// construction, so global min = min over rays of sample 0, global max = max
// over rays of sample 95. Max encoded as atomicMin of ~bits (depths >= 0),
// so both ws slots init 0xFFFFFFFF -> single 8-byte memset.
// ---------------------------------------------------------------------------
__global__ void depth_minmax_sorted(const float* __restrict__ deps, unsigned* ws) {
    const int t = blockIdx.x * blockDim.x + threadIdx.x;   // grid covers exactly NRAYS
    float lo = deps[(size_t)t * NS];
    float hi = deps[(size_t)t * NS + (NS - 1)];
    #pragma unroll
    for (int off = 32; off; off >>= 1) {
        lo = fminf(lo, __shfl_xor(lo, off, 64));
        hi = fmaxf(hi, __shfl_xor(hi, off, 64));
    }
    if ((threadIdx.x & 63) == 0) {
        atomicMin(&ws[0], __float_as_uint(lo));
        atomicMin(&ws[1], ~__float_as_uint(hi));   // max via inverted-bit min
    }
}

__device__ __forceinline__ float softplus_fast(float x) {
    // softplus = max(x,0) + log(1 + exp(-|x|)); __logf/__expf are single
    // v_log/v_exp instrs (~1e-6 rel err; tolerance headroom ~6x).
    return fmaxf(x, 0.0f) + __logf(1.0f + __expf(-fabsf(x)));
}

// Fire-and-forget global->LDS DMA, 16 B per active lane, dest = uniform LDS
// base + lane*16 (linear). No destination VGPRs -> cannot be sunk/remat'd.
__device__ __forceinline__ void gload_lds16(const float* gp, float* lp) {
    __builtin_amdgcn_global_load_lds(
        (const __attribute__((address_space(1))) void*)gp,
        (__attribute__((address_space(3))) void*)lp,
        16, 0, 0);
}

// Per-buffer float layout (3072 floats = 12288 B):
//   c [0,1152) | p [1152,2304) | d [2304,2688) | n [2688,3072)
// Exactly 14 vmem instructions per call (the counted-vmcnt unit).
__device__ __forceinline__ void issue_dma(const float* __restrict__ colors,
                                          const float* __restrict__ coords,
                                          const float* __restrict__ deps,
                                          const float* __restrict__ dens,
                                          int grp, float* lbuf, int lane) {
    const size_t rb0 = (size_t)grp * 4;            // first ray of the group
    const float* cg = colors + rb0 * (NS * 3);
    const float* pg = coords + rb0 * (NS * 3);
    const float* dg = deps   + rb0 * NS;
    const float* ng = dens   + rb0 * NS;
    #pragma unroll
    for (int k = 0; k < 4; ++k) gload_lds16(cg + 4 * lane + 256 * k, lbuf + 256 * k);
    #pragma unroll
    for (int k = 0; k < 4; ++k) gload_lds16(pg + 4 * lane + 256 * k, lbuf + 1152 + 256 * k);
    gload_lds16(dg + 4 * lane, lbuf + 2304);
    gload_lds16(ng + 4 * lane, lbuf + 2688);
    if (lane < 32) {                               // 512-B tails
        gload_lds16(cg + 1024 + 4 * lane, lbuf + 1024);
        gload_lds16(pg + 1024 + 4 * lane, lbuf + 1152 + 1024);
        gload_lds16(dg +  256 + 4 * lane, lbuf + 2304 + 256);
        gload_lds16(ng +  256 + 4 * lane, lbuf + 2688 + 256);
    }
}

// ---------------------------------------------------------------------------
// R7: persistent waves + double-buffered DMA pipeline. R1-R6 post-mortem:
// six structures all pinned at 74-90 us because all used 16384 SHORT-LIVED
// waves; measured wave lifetime (occupancy x time / waves-per-CU) is
// 12-22 us vs ~1 us of work -- per-wave cold-start/launch/drain dominates
// and no internal restructuring can fix it. Here: 256 blocks (1/CU, LDS
// 98304 B), 4 waves each, each wave loops over 16 wave-groups with
// two wave-private LDS buffers. Loop: counted s_waitcnt vmcnt(14) (only the
// NEXT tile's 14 DMAs may remain in flight; in-order load retirement makes
// this safe independent of store count), consume + compute + store, then
// issue DMA two tiles ahead into the just-freed buffer. Steady-state: each
// DMA has a full iteration (~2 us >> 900 cy) to land -> no memory stalls;
// launch cost amortized 16x. Value path identical to verified R1-R6
// (d/n/c/p neighbors now read from LDS instead of shuffle).
// ---------------------------------------------------------------------------
__launch_bounds__(256, 1)
__global__ void raymarch(const float* __restrict__ colors,
                         const float* __restrict__ dens,
                         const float* __restrict__ deps,
                         const float* __restrict__ coords,
                         const int* __restrict__ wbp,
                         const unsigned* __restrict__ mm,
                         float* __restrict__ out) {
    __shared__ float sbuf[4 * 2 * 3072];   // 98304 B: 4 waves x 2 buffers

    const int tid  = threadIdx.x;
    const int lane = tid & 63;
    const int wv   = tid >> 6;                    // wave in block (0..3)
    const int sub  = lane & 15;                   // position within ray group
    const int r4   = lane >> 4;                   // ray within wave-group (0..3)
    const int gbase = blockIdx.x * 64;            // 64 wave-groups per block

    float* wreg = sbuf + wv * 6144;               // this wave's 2 buffers

    // prologue: fill both buffers (iterations 0 and 1)
    issue_dma(colors, coords, deps, dens, gbase + 0 * 4 + wv, wreg,        lane);
    issue_dma(colors, coords, deps, dens, gbase + 1 * 4 + wv, wreg + 3072, lane);

    for (int it = 0; it < 16; ++it) {
        float* lb = wreg + (it & 1) * 3072;

        // Buffer `it` ready: only the newest 14 vmem ops (next tile's DMA)
        // may remain outstanding. Loads retire in issue order, so <=14 total
        // outstanding implies this tile's DMA has landed. Last iteration has
        // no next-tile DMA -> full drain.
        if (it < 15) asm volatile("s_waitcnt vmcnt(14)" ::: "memory");
        else         asm volatile("s_waitcnt vmcnt(0)"  ::: "memory");
        __builtin_amdgcn_sched_barrier(0);

        const int grp = gbase + it * 4 + wv;
        const int g   = grp * 4 + r4;             // global ray id

        // ---- per-lane slices from LDS ----
        float d[6], n[6], d6, n6;
        {
            const float2* qd = (const float2*)(lb + 2304 + r4 * 96 + 6 * sub);
            const float2* qn = (const float2*)(lb + 2688 + r4 * 96 + 6 * sub);
            #pragma unroll
            for (int j = 0; j < 3; ++j) { float2 v = qd[j]; d[2*j] = v.x; d[2*j+1] = v.y; }
            #pragma unroll
            for (int j = 0; j < 3; ++j) { float2 v = qn[j]; n[2*j] = v.x; n[2*j+1] = v.y; }
            const int noff = (sub < 15) ? 6 * (sub + 1) : 0;   // dummy for sub 15
            d6 = lb[2304 + r4 * 96 + noff];
            n6 = lb[2688 + r4 * 96 + noff];
        }
        float c[18], p[18], cn0, cn1, cn2, pn0, pn1, pn2;
        {
            const float2* qc = (const float2*)(lb + r4 * 288 + 18 * sub);
            const float2* qp = (const float2*)(lb + 1152 + r4 * 288 + 18 * sub);
            #pragma unroll
            for (int j = 0; j < 9; ++j) { float2 v = qc[j]; c[2*j] = v.x; c[2*j+1] = v.y; }
            #pragma unroll
            for (int j = 0; j < 9; ++j) { float2 v = qp[j]; p[2*j] = v.x; p[2*j+1] = v.y; }
            const int noff = (sub < 15) ? 18 * (sub + 1) : 0;
            cn0 = lb[r4 * 288 + noff + 0];
            cn1 = lb[r4 * 288 + noff + 1];
            cn2 = lb[r4 * 288 + noff + 2];
            pn0 = lb[1152 + r4 * 288 + noff + 0];
            pn1 = lb[1152 + r4 * 288 + noff + 1];
            pn2 = lb[1152 + r4 * 288 + noff + 2];
        }

        // ---- per-interval alpha / transmittance factor ----
        float a[6], f[6];
        #pragma unroll
        for (int i = 0; i < 6; ++i) {
            float dn1 = (i < 5) ? d[i+1] : d6;
            float nn1 = (i < 5) ? n[i+1] : n6;
            float E = __expf(-softplus_fast(0.5f * (n[i] + nn1)) * (dn1 - d[i]));
            const bool valid = (i < 5) || (sub < 15);    // compile-time except i==5
            a[i] = valid ? (1.0f - E) : 0.0f;
            f[i] = valid ? (E + 1e-10f) : 1.0f;
        }

        // ---- inclusive scan over the 16-lane group ----
        float incl = ((f[0] * f[1]) * (f[2] * f[3])) * (f[4] * f[5]);
        #pragma unroll
        for (int off = 1; off < 16; off <<= 1) {
            float t = __shfl_up(incl, off, 16);
            if (sub >= off) incl *= t;
        }
        float excl = __shfl_up(incl, 1, 16);
        if (sub == 0) excl = 1.0f;

        // ---- weights (direct scatter, L2-merged) + composite partials ----
        float acc[8];
        #pragma unroll
        for (int k = 0; k < 8; ++k) acc[k] = 0.0f;
        float t = excl;
        float tauc = 0.0f;
        const size_t wb = (size_t)OFF_W + (size_t)g * NI + 6 * sub;
        #pragma unroll
        for (int i = 0; i < 6; ++i) {
            float w = a[i] * t;
            if (i < 5 || sub < 15) out[wb + i] = w;      // weights output
            float dn1 = (i < 5) ? d[i+1] : d6;
            float dm  = 0.5f * (d[i] + dn1);
            float cmx = 0.5f * (c[3*i+0] + ((i < 5) ? c[3*i+3] : cn0));
            float cmy = 0.5f * (c[3*i+1] + ((i < 5) ? c[3*i+4] : cn1));
            float cmz = 0.5f * (c[3*i+2] + ((i < 5) ? c[3*i+5] : cn2));
            float pmx = 0.5f * (p[3*i+0] + ((i < 5) ? p[3*i+3] : pn0));
            float pmy = 0.5f * (p[3*i+1] + ((i < 5) ? p[3*i+4] : pn1));
            float pmz = 0.5f * (p[3*i+2] + ((i < 5) ? p[3*i+5] : pn2));
            acc[0] += w * cmx;  acc[1] += w * cmy;  acc[2] += w * cmz;
            acc[3] += w * pmx;  acc[4] += w * pmy;  acc[5] += w * pmz;
            acc[6] += w * dm;   acc[7] += w;
            if (i == 4) tauc = t;      // lane sub==15, i==4: t == trans[94] == tau
            t *= f[i];
        }
        float tau = __shfl(tauc, (lane & 48) | 15, 64);

        // ---- reduce 8 accumulators across the 16-lane group ----
        #pragma unroll
        for (int k = 0; k < 8; ++k) {
            #pragma unroll
            for (int off = 1; off < 16; off <<= 1)
                acc[k] += __shfl_xor(acc[k], off, 64);
        }

        if (sub == 0) {
            float add = (wbp != nullptr && wbp[0] != 0) ? (1.0f - acc[7]) : 0.0f;
            size_t rb = (size_t)OFF_RGB + (size_t)g * 3;
            out[rb + 0] = acc[0] + add;
            out[rb + 1] = acc[1] + add;
            out[rb + 2] = acc[2] + add;
            size_t pb = (size_t)OFF_PT + (size_t)g * 3;
            out[pb + 0] = acc[3];
            out[pb + 1] = acc[4];
            out[pb + 2] = acc[5];
            float cd = acc[6];
            if (cd != cd) cd = __int_as_float(0x7f800000);   // nan_to_num -> +inf
            float dmin = __uint_as_float(mm[0]);
            float dmax = __uint_as_float(~mm[1]);
            cd = fminf(fmaxf(cd, dmin), dmax);               // jnp.clip(global min/max)
            out[OFF_DEPTH + g] = cd;
            out[OFF_TAU + g]   = tau;
        }

        // ---- issue DMA two tiles ahead into the just-freed buffer ----
        if (it < 14) {
            __builtin_amdgcn_sched_barrier(0);
            issue_dma(colors, coords, deps, dens, gbase + (it + 2) * 4 + wv, lb, lane);
        }
    }
}

extern "C" void kernel_launch(void* const* d_in, const int* in_sizes, int n_in,
                              void* d_out, int out_size, void* d_ws, size_t ws_size,
                              hipStream_t stream) {
    const float* colors = (const float*)d_in[0];
    const float* dens   = (const float*)d_in[1];
    const float* deps   = (const float*)d_in[2];
    const float* coords = (const float*)d_in[3];
    const int*   wb     = (n_in > 4) ? (const int*)d_in[4] : nullptr;
    float* out = (float*)d_out;
    unsigned* mm = (unsigned*)d_ws;

    // Both slots init 0xFFFFFFFF (min slot: uint-max; max slot stores ~bits).
    hipMemsetAsync(mm, 0xFF, 8, stream);
    depth_minmax_sorted<<<NRAYS / 256, 256, 0, stream>>>(deps, mm);
    raymarch<<<256, 256, 0, stream>>>(colors, dens, deps, coords, wb, mm, out);
}